// Round 4
// baseline (1316.293 us; speedup 1.0000x reference)
//
#include <hip/hip_runtime.h>

#define N_NODES 100000
#define D 64
#define SCAN_CHUNK 256
#define NBLK_SCAN ((N_NODES + SCAN_CHUNK - 1) / SCAN_CHUNK)  // 391

__device__ __forceinline__ unsigned f2bf(float f) {  // RNE float->bf16 bits
  unsigned u = __float_as_uint(f);
  return (u + 0x7fffu + ((u >> 16) & 1u)) >> 16;
}
#define BF_LO(u) __uint_as_float(((unsigned)(u)) << 16)
#define BF_HI(u) __uint_as_float(((unsigned)(u)) & 0xffff0000u)

// ---------- bf16-ize feature table (8 floats / thread) ----------
__global__ void to_bf16_kernel(const float4* __restrict__ in,
                               uint4* __restrict__ outp, int n8) {
  int i = blockIdx.x * blockDim.x + threadIdx.x;
  int stride = gridDim.x * blockDim.x;
  for (; i < n8; i += stride) {
    float4 a = in[2 * i], b = in[2 * i + 1];
    uint4 r;
    r.x = f2bf(a.x) | (f2bf(a.y) << 16);
    r.y = f2bf(a.z) | (f2bf(a.w) << 16);
    r.z = f2bf(b.x) | (f2bf(b.y) << 16);
    r.w = f2bf(b.z) | (f2bf(b.w) << 16);
    outp[i] = r;
  }
}

// ---------- CSR build ----------
__global__ void hist_kernel(const int* __restrict__ dst, int* __restrict__ degI,
                            int nE) {
  int i = blockIdx.x * blockDim.x + threadIdx.x;
  int stride = gridDim.x * blockDim.x;
  for (int e = i; e < nE; e += stride) atomicAdd(&degI[dst[e]], 1);
}

__global__ void scan_p1(const int* __restrict__ degI, int* __restrict__ bsum) {
  int t = threadIdx.x, b = blockIdx.x;
  int i = b * SCAN_CHUNK + t;
  int v = (i < N_NODES) ? degI[i] : 0;
  for (int off = 32; off; off >>= 1) v += __shfl_down(v, off);
  __shared__ int ws4[4];
  if ((t & 63) == 0) ws4[t >> 6] = v;
  __syncthreads();
  if (t == 0) bsum[b] = ws4[0] + ws4[1] + ws4[2] + ws4[3];
}

__global__ void scan_p2(int* __restrict__ bsum, int nB) {
  __shared__ int s[512];
  int t = threadIdx.x;
  int orig = (t < nB) ? bsum[t] : 0;
  s[t] = orig;
  __syncthreads();
  for (int off = 1; off < 512; off <<= 1) {
    int v = (t >= off) ? s[t - off] : 0;
    __syncthreads();
    s[t] += v;
    __syncthreads();
  }
  if (t < nB) bsum[t] = s[t] - orig;
}

__global__ void scan_p3(const int* __restrict__ degI, const int* __restrict__ bsum,
                        int* __restrict__ rowstart, int* __restrict__ cursor) {
  __shared__ int s[SCAN_CHUNK];
  int t = threadIdx.x, b = blockIdx.x;
  int i = b * SCAN_CHUNK + t;
  int d = (i < N_NODES) ? degI[i] : 0;
  s[t] = d;
  __syncthreads();
  for (int off = 1; off < SCAN_CHUNK; off <<= 1) {
    int v = (t >= off) ? s[t - off] : 0;
    __syncthreads();
    s[t] += v;
    __syncthreads();
  }
  if (i < N_NODES) {
    int ex = s[t] - d + bsum[b];
    rowstart[i] = ex;
    cursor[i] = ex;
  }
}

__global__ void build_adj_kernel(const int* __restrict__ src,
                                 const int* __restrict__ dst,
                                 int* __restrict__ cursor, int* __restrict__ adj,
                                 int nE) {
  int i = blockIdx.x * blockDim.x + threadIdx.x;
  int stride = gridDim.x * blockDim.x;
  for (int e = i; e < nE; e += stride) {
    int d = dst[e];
    int p = atomicAdd(&cursor[d], 1);
    adj[p] = src[e];
  }
}

// ---------- Fused SAGE layer v3 (bf16 gather) ----------
// Wave-per-node. lane = o*8 + j8 : o = edge slot (gather) / k-range (GEMV),
// j8 = 16B feature chunk (8 bf16). Gather: 8 edges per wave-load, 16 in
// flight per iteration. GEMV: lane owns outputs 8*j8..+7 over k in
// [8o,8o+8); W bf16 in LDS (rows padded to 160B; octet-phased b128 reads
// are bank-conflict-free); mean/x broadcast via in-register shfl.

#define ACC8(v, m)                          \
  acc[0] = fmaf(BF_LO(v.x), m, acc[0]);     \
  acc[1] = fmaf(BF_HI(v.x), m, acc[1]);     \
  acc[2] = fmaf(BF_LO(v.y), m, acc[2]);     \
  acc[3] = fmaf(BF_HI(v.y), m, acc[3]);     \
  acc[4] = fmaf(BF_LO(v.z), m, acc[4]);     \
  acc[5] = fmaf(BF_HI(v.z), m, acc[5]);     \
  acc[6] = fmaf(BF_LO(v.w), m, acc[6]);     \
  acc[7] = fmaf(BF_HI(v.w), m, acc[7]);

__global__ __launch_bounds__(256, 6) void sage_fused_v3(
    const int* __restrict__ rowstart, const int* __restrict__ degI,
    const int* __restrict__ adj,
    const float* __restrict__ selfF,    // f32 self features (mode 0)
    const unsigned short* __restrict__ selfB,  // bf16 self features (mode 1)
    const unsigned short* __restrict__ gatB,   // bf16 gather table
    const float* __restrict__ Wl, const float* __restrict__ bl,
    const float* __restrict__ Wr, const float* __restrict__ Wc,
    const float* __restrict__ bc,
    float* __restrict__ outF, unsigned short* __restrict__ outB,
    int nE, int mode) {
  __shared__ unsigned short WT[2][64 * 80];  // [mat][k*80 + j], 160B rows
  int tid = threadIdx.x;
  for (int i = tid; i < 4096; i += 256) {
    int k = i >> 6, j = i & 63;  // lanes of a wave share k -> 2B-stride writes
    WT[0][k * 80 + j] = (unsigned short)f2bf(Wl[j * 64 + k]);
    WT[1][k * 80 + j] = (unsigned short)f2bf(Wr[j * 64 + k]);
  }
  __syncthreads();

  int lane = tid & 63;
  int o = lane >> 3, j8 = lane & 7;
  float blv[8];
  {
    float4 b0 = ((const float4*)bl)[2 * j8], b1 = ((const float4*)bl)[2 * j8 + 1];
    blv[0] = b0.x; blv[1] = b0.y; blv[2] = b0.z; blv[3] = b0.w;
    blv[4] = b1.x; blv[5] = b1.y; blv[6] = b1.z; blv[7] = b1.w;
  }

  int gw = (blockIdx.x * 256 + tid) >> 6;
  int nWaves = (gridDim.x * 256) >> 6;

  for (int n = gw; n < N_NODES; n += nWaves) {
    int rs = rowstart[n], dg = degI[n];
    float acc[8] = {0.f, 0.f, 0.f, 0.f, 0.f, 0.f, 0.f, 0.f};
    for (int base = 0; base < dg; base += 64) {
      int cnt = min(dg - base, 64);
      int a = adj[min(rs + base + lane, nE - 1)];
      for (int t = 0; t < cnt; t += 16) {
        int el0 = t + o, el1 = t + 8 + o;  // both <= 63
        int nb0 = __shfl(a, el0);
        int nb1 = __shfl(a, el1);
        bool ok0 = el0 < cnt, ok1 = el1 < cnt;
        nb0 = ok0 ? nb0 : n;
        nb1 = ok1 ? nb1 : n;
        uint4 v0 = *(const uint4*)(gatB + (size_t)nb0 * 64 + j8 * 8);
        uint4 v1 = *(const uint4*)(gatB + (size_t)nb1 * 64 + j8 * 8);
        float m0 = ok0 ? 1.f : 0.f, m1 = ok1 ? 1.f : 0.f;
        ACC8(v0, m0)
        ACC8(v1, m1)
      }
    }
    // reduce partial sums across the 8 edge-slots (lane bits 3,4,5)
#pragma unroll
    for (int jj = 0; jj < 8; ++jj) {
      acc[jj] += __shfl_xor(acc[jj], 8);
      acc[jj] += __shfl_xor(acc[jj], 16);
      acc[jj] += __shfl_xor(acc[jj], 32);
    }
    float inv = 1.f / (float)max(dg, 1);
#pragma unroll
    for (int jj = 0; jj < 8; ++jj) acc[jj] *= inv;  // acc = mean chunk j8

    // self features, chunk j8
    float xs[8];
    if (mode == 0) {
      const float4* sf = (const float4*)selfF;
      float4 a0 = sf[(size_t)n * 16 + 2 * j8], a1 = sf[(size_t)n * 16 + 2 * j8 + 1];
      xs[0] = a0.x; xs[1] = a0.y; xs[2] = a0.z; xs[3] = a0.w;
      xs[4] = a1.x; xs[5] = a1.y; xs[6] = a1.z; xs[7] = a1.w;
    } else {
      uint4 v = *(const uint4*)(selfB + (size_t)n * 64 + j8 * 8);
      xs[0] = BF_LO(v.x); xs[1] = BF_HI(v.x);
      xs[2] = BF_LO(v.y); xs[3] = BF_HI(v.y);
      xs[4] = BF_LO(v.z); xs[5] = BF_HI(v.z);
      xs[6] = BF_LO(v.w); xs[7] = BF_HI(v.w);
    }

    // dual GEMV: lane (o,j8) -> outputs 8*j8..+7 over k in [8o, 8o+8)
    float ov[8] = {0.f, 0.f, 0.f, 0.f, 0.f, 0.f, 0.f, 0.f};
    const unsigned short* wlp = &WT[0][0] + (o * 8) * 80 + j8 * 8;
    const unsigned short* wrp = &WT[1][0] + (o * 8) * 80 + j8 * 8;
#pragma unroll
    for (int i = 0; i < 8; ++i) {
      uint4 wl = *(const uint4*)(wlp + i * 80);
      uint4 wr = *(const uint4*)(wrp + i * 80);
      float mk = __shfl(acc[i], o);  // mean[8o+i] lives in lane o, comp i
      float xk = __shfl(xs[i], o);
      ov[0] = fmaf(mk, BF_LO(wl.x), fmaf(xk, BF_LO(wr.x), ov[0]));
      ov[1] = fmaf(mk, BF_HI(wl.x), fmaf(xk, BF_HI(wr.x), ov[1]));
      ov[2] = fmaf(mk, BF_LO(wl.y), fmaf(xk, BF_LO(wr.y), ov[2]));
      ov[3] = fmaf(mk, BF_HI(wl.y), fmaf(xk, BF_HI(wr.y), ov[3]));
      ov[4] = fmaf(mk, BF_LO(wl.z), fmaf(xk, BF_LO(wr.z), ov[4]));
      ov[5] = fmaf(mk, BF_HI(wl.z), fmaf(xk, BF_HI(wr.z), ov[5]));
      ov[6] = fmaf(mk, BF_LO(wl.w), fmaf(xk, BF_LO(wr.w), ov[6]));
      ov[7] = fmaf(mk, BF_HI(wl.w), fmaf(xk, BF_HI(wr.w), ov[7]));
    }
    // reduce over k-ranges (lane bits 3,4,5), then bias
#pragma unroll
    for (int jj = 0; jj < 8; ++jj) {
      ov[jj] += __shfl_xor(ov[jj], 8);
      ov[jj] += __shfl_xor(ov[jj], 16);
      ov[jj] += __shfl_xor(ov[jj], 32);
      ov[jj] += blv[jj];
    }

    if (mode == 0) {
      // relu + store bf16 h1 (one lane per j8)
#pragma unroll
      for (int jj = 0; jj < 8; ++jj) ov[jj] = fmaxf(ov[jj], 0.f);
      if (o == 0) {
        uint4 p;
        p.x = f2bf(ov[0]) | (f2bf(ov[1]) << 16);
        p.y = f2bf(ov[2]) | (f2bf(ov[3]) << 16);
        p.z = f2bf(ov[4]) | (f2bf(ov[5]) << 16);
        p.w = f2bf(ov[6]) | (f2bf(ov[7]) << 16);
        *(uint4*)(outB + (size_t)n * 64 + j8 * 8) = p;
      }
    } else {
      // fused classifier
      const float4* wc4 = (const float4*)Wc;
      float4 c00 = wc4[2 * j8], c01 = wc4[2 * j8 + 1];
      float4 c10 = wc4[16 + 2 * j8], c11 = wc4[16 + 2 * j8 + 1];
      float p0 = ov[0] * c00.x + ov[1] * c00.y + ov[2] * c00.z + ov[3] * c00.w +
                 ov[4] * c01.x + ov[5] * c01.y + ov[6] * c01.z + ov[7] * c01.w;
      float p1 = ov[0] * c10.x + ov[1] * c10.y + ov[2] * c10.z + ov[3] * c10.w +
                 ov[4] * c11.x + ov[5] * c11.y + ov[6] * c11.z + ov[7] * c11.w;
      p0 += __shfl_xor(p0, 1); p0 += __shfl_xor(p0, 2); p0 += __shfl_xor(p0, 4);
      p1 += __shfl_xor(p1, 1); p1 += __shfl_xor(p1, 2); p1 += __shfl_xor(p1, 4);
      if (lane == 0) {
        outF[(size_t)n * 2 + 0] = p0 + bc[0];
        outF[(size_t)n * 2 + 1] = p1 + bc[1];
      }
    }
  }
}

extern "C" void kernel_launch(void* const* d_in, const int* in_sizes, int n_in,
                              void* d_out, int out_size, void* d_ws,
                              size_t ws_size, hipStream_t stream) {
  const float* x   = (const float*)d_in[0];
  const int*   ei  = (const int*)d_in[1];
  const float* Wl1 = (const float*)d_in[2];
  const float* bl1 = (const float*)d_in[3];
  const float* Wr1 = (const float*)d_in[4];
  const float* Wl2 = (const float*)d_in[5];
  const float* bl2 = (const float*)d_in[6];
  const float* Wr2 = (const float*)d_in[7];
  const float* Wc  = (const float*)d_in[8];
  const float* bc  = (const float*)d_in[9];
  float* out = (float*)d_out;

  int nE = in_sizes[1] / 2;
  const int* src = ei;
  const int* dst = ei + nE;

  // Workspace: xb [N*64 bf16] | h1b [N*64 bf16] | degI [N] | rowstart [N] |
  //            cursor [N] | bsum [512] | adj [E]   (~31.6 MB)
  unsigned short* xb  = (unsigned short*)d_ws;
  unsigned short* h1b = xb + (size_t)N_NODES * D;
  int* degI = (int*)(h1b + (size_t)N_NODES * D);
  int* rowstart = degI + N_NODES;
  int* cursor = rowstart + N_NODES;
  int* bsum = cursor + N_NODES;
  int* adj = bsum + 512;

  hipMemsetAsync(degI, 0, N_NODES * sizeof(int), stream);

  dim3 blk(256);
  to_bf16_kernel<<<1024, blk, 0, stream>>>((const float4*)x, (uint4*)xb,
                                           N_NODES * D / 8);
  hist_kernel<<<2048, blk, 0, stream>>>(dst, degI, nE);
  scan_p1<<<NBLK_SCAN, blk, 0, stream>>>(degI, bsum);
  scan_p2<<<1, 512, 0, stream>>>(bsum, NBLK_SCAN);
  scan_p3<<<NBLK_SCAN, blk, 0, stream>>>(degI, bsum, rowstart, cursor);
  build_adj_kernel<<<2048, blk, 0, stream>>>(src, dst, cursor, adj, nE);

  // Layer 1: gather xb, self x(f32) -> h1b (bf16, relu)
  sage_fused_v3<<<1536, blk, 0, stream>>>(rowstart, degI, adj, x, xb, xb, Wl1,
                                          bl1, Wr1, Wc, bc, out, h1b, nE, 0);
  // Layer 2: gather h1b, self h1b -> out (f32, fused classifier)
  sage_fused_v3<<<1536, blk, 0, stream>>>(rowstart, degI, adj, x, h1b, h1b,
                                          Wl2, bl2, Wr2, Wc, bc, out, h1b, nE,
                                          1);
}